// Round 6
// baseline (11152.329 us; speedup 1.0000x reference)
//
#include <hip/hip_runtime.h>
#include <math.h>

// PhaseNN: phase-oscillator ODE integrator on MI355X.
// Design:
//   grid = 256 blocks = 32 row-groups (8 batch rows) x 8 N-slices (128 cols), 256 thr/block.
//   cos/sin(xi) slice tables pre-converted to bf16 MFMA A-fragments held in REGISTERS.
//   Per eval: pack cos/sin(phi) -> GEMM1 (m partial, 16x16x32 bf16 MFMA) -> ONE exchange
//   + barrier -> redundant reduce + softmax -> GEMM2 -> RK4 combine (fp32).
// Round-5 lesson: cost is IF$ LATENCY (~0.4-1 us/round-trip), not bytes. 320 MB of
//   FETCH was flag-poll refetches (~19 iters x 0.4 us x 2 barriers = 12 us/eval).
// Round-6 move: L2-LOCAL exchange via WORKGROUP-scope global atomic RMWs.
//   All global atomic RMWs execute in the TCC (L2) and bypass the stale-prone L1:
//   publish = atomic_exchange (no sc bits -> local L2), read/poll = fetch_add(0).
//   Coherent only if the 8 group peers share an XCD -> PROBE at startup (swap magic,
//   slow AGENT barrier, one RMW read of all 8; unanimity => fast mode). Every eval we
//   DUAL-publish (fast swaps + slow sc1 stores; one vmcnt drain) so the proven Round-5
//   slow path is always available; fast polls have an iteration cap with sticky
//   downgrade -> no code path can hang. No inline asm, no s_getreg (Rounds-3/4 suspects).
// ws: [0,1 MiB) fast pm (2 parity x 256 slots x 2 KB, bf16-packed);
//     [1,2 MiB) slow pm (same layout, sc1);
//     [2 MiB, +16 KiB) ctrl: fast flags (256 x 32 B), slow flags (256 x 16 B),
//     probe (256 x 16 B). Footprint identical to the proven 2 MiB + 16 KiB.

typedef __attribute__((ext_vector_type(4))) float f32x4;
typedef __attribute__((ext_vector_type(8))) short bf16x8;
typedef __attribute__((ext_vector_type(4))) unsigned short u16x4;

struct TCons { float s[64]; float c[64]; };

#define PROBE_MAGIC 0x51AFE123u
#define FAST_TIMEOUT 65536

__device__ __forceinline__ unsigned short f2bf(float f) {
  unsigned u = __builtin_bit_cast(unsigned, f);
  return (unsigned short)((u + 0x7FFFu + ((u >> 16) & 1u)) >> 16);
}
__device__ __forceinline__ float ubf(unsigned short u) {
  unsigned x = ((unsigned)u) << 16;
  return __builtin_bit_cast(float, x);
}
__device__ __forceinline__ unsigned long long pack4bf(float a, float b, float c, float d) {
  return (unsigned long long)f2bf(a)
       | ((unsigned long long)f2bf(b) << 16)
       | ((unsigned long long)f2bf(c) << 32)
       | ((unsigned long long)f2bf(d) << 48);
}

__global__ __launch_bounds__(256, 1) void phasenn_kernel(
    const float* __restrict__ x, const float* __restrict__ W_enc,
    const float* __restrict__ b_enc, const float* __restrict__ xi,
    const float* __restrict__ W_out, const float* __restrict__ b_out,
    float* __restrict__ dout, char* __restrict__ wsb,
    unsigned int* __restrict__ ctrl, TCons tc)
{
  __shared__ __align__(16) char  A1c[8448];   // A1 (16x256 bf16, swizzled) / coup (2x8x132 f32) overlay
  __shared__ __align__(16) char  wtc[4096];   // w  (16x128 bf16, swizzled; pad rows zero)
  __shared__ __align__(16) float csf[2048];   // [0..1023]=cos(pw), [1024..2047]=sin(pw), fp32
  __shared__ __align__(16) float phi0s[1024]; // 8 rows x 128 cols
  __shared__ __align__(16) float kaccs[1024];
  __shared__ __align__(16) float pws[1024];
  __shared__ __align__(16) float xst[8*784];  // staged x rows (encoder only)
  __shared__ int modeSh;                      // 1 = fast (L2 exchange), 0 = slow (IF$)

  const int tid  = threadIdx.x;
  const int g    = blockIdx.x & 31;   // row-group (peers {g+32k} == g mod 8 -> same XCD if round-robin)
  const int j    = blockIdx.x >> 5;   // N-slice
  const int jn0  = j << 7;
  const int wave = tid >> 6;
  const int lane = tid & 63;
  const int b16  = lane & 15;
  const int q    = lane >> 4;
  const int slot = g*8 + j;

  char* fastmp = wsb;                 // 2 parity x 256 slots x 2048 B (L2-local)
  char* slowmp = wsb + (1 << 20);     // same layout, sc1 (IF$)
  unsigned int* fastF = ctrl;         // 256 slots x 8 words (32 B)
  unsigned int* slowF = ctrl + 2048;  // 256 slots x 4 words (16 B)
  unsigned int* probe = ctrl + 3072;  // 256 slots x 4 words (16 B)

  // ---- prologue: zero w-table (pad rows b>=8 must stay 0)
  for (int idx = tid; idx < 2048; idx += 256) ((unsigned short*)wtc)[idx] = 0;

  // ---- prologue: stage x rows into LDS
  for (int idx = tid; idx < 8*784; idx += 256) {
    int bb = idx / 784;
    xst[idx] = x[(g*8 + bb)*784 + (idx - bb*784)];
  }
  __syncthreads();

  // ---- prologue: encoder  phi0 = 2pi*sigmoid(x @ W_enc^T + b_enc)  (fp32 VALU)
  {
    const int b = tid >> 5, nl = (tid & 31) << 2;
    #pragma unroll
    for (int u = 0; u < 4; ++u) {
      const int ng = jn0 + nl + u;
      const float* wr = W_enc + ng*784;
      const float* xr = xst + b*784;
      float acc = b_enc[ng];
      #pragma unroll 4
      for (int d = 0; d < 784; d += 4) {
        f32x4 wv = *(const f32x4*)(wr + d);
        f32x4 xv = *(const f32x4*)(xr + d);
        acc += wv[0]*xv[0] + wv[1]*xv[1] + wv[2]*xv[2] + wv[3]*xv[3];
      }
      float ph = 6.283185307179586f / (1.0f + __expf(-acc));
      phi0s[b*128 + nl + u] = ph;
      pws  [b*128 + nl + u] = ph;
    }
  }

  // ---- prologue: build table fragments in registers (bf16)
  // GEMM1 (transposed): D[p][b] = sum_k T1[p][k] * A1[k][b]
  bf16x8 t1f[2][8];
  #pragma unroll
  for (int tt = 0; tt < 2; ++tt) {
    const int p = (wave*2 + tt)*16 + b16;
    #pragma unroll
    for (int kk = 0; kk < 8; ++kk) {
      const int base = (kk & 3)*32 + q*8;
      const float* src = xi + p*1024 + jn0 + base;
      f32x4 v0 = *(const f32x4*)(src);
      f32x4 v1 = *(const f32x4*)(src + 4);
      bf16x8 fr;
      #pragma unroll
      for (int i = 0; i < 8; ++i) {
        float xv = (i < 4) ? v0[i] : v1[i-4];
        float t  = (kk < 4) ? cosf(xv) : sinf(xv);
        fr[i] = (short)f2bf(t);
      }
      t1f[tt][kk] = fr;
    }
  }
  // GEMM2 (transposed): D[c][b] = sum_p T2[c][p] * w[p][b]
  bf16x8 t2f[4][4];
  #pragma unroll
  for (int u = 0; u < 4; ++u) {
    const int c   = (wave + 4*u)*16 + b16;
    const int col = jn0 + (c & 127);
    const bool isc = (c < 128);
    #pragma unroll
    for (int kk = 0; kk < 4; ++kk) {
      bf16x8 fr;
      #pragma unroll
      for (int i = 0; i < 8; ++i) {
        const int p = kk*32 + q*8 + i;
        float xv = xi[p*1024 + col];
        fr[i] = (short)f2bf(isc ? cosf(xv) : sinf(xv));
      }
      t2f[u][kk] = fr;
    }
  }

  // ---- probe: publish magic via L2-local RMW; slow barrier; single RMW read of peers.
  // Same-XCD peer's swap lives (dirty) in our shared TCC -> read returns MAGIC.
  // Cross-XCD peer's swap is dirty in a REMOTE L2 -> our TCC fetches stale 0 from IF$
  // -> unanimous slow. (Eviction+writeback inside the quiet barrier window is the only
  // mis-detect path; ~100 KB of traffic vs a 4 MiB L2 makes that negligible, and even
  // then the poll timeout downgrades safely.)
  if (tid == 0) {
    unsigned o = __hip_atomic_exchange(probe + slot*4, PROBE_MAGIC,
                                       __ATOMIC_RELAXED, __HIP_MEMORY_SCOPE_WORKGROUP);
    (void)o;
  }
  __syncthreads();   // drain the swap
  if (tid == 0)
    __hip_atomic_store(slowF + slot*4, 1u, __ATOMIC_RELAXED, __HIP_MEMORY_SCOPE_AGENT);
  if (tid < 8) {
    while (__hip_atomic_load(slowF + (g*8 + tid)*4,
                             __ATOMIC_RELAXED, __HIP_MEMORY_SCOPE_AGENT) < 1u)
      __builtin_amdgcn_s_sleep(2);
  }
  __syncthreads();
  if (tid < 8) {
    unsigned pv = __hip_atomic_fetch_add(probe + (g*8 + tid)*4, 0u,
                                         __ATOMIC_RELAXED, __HIP_MEMORY_SCOPE_WORKGROUP);
    unsigned long long bl = __ballot(pv == PROBE_MAGIC);
    if (tid == 0) modeSh = ((bl & 0xFFull) == 0xFFull) ? 1 : 0;
  }
  __syncthreads();

  const float dtf = 0.03125f, half = 0.015625f;
  const float sixth = (float)(0.03125/6.0);

  for (int e = 0; e < 64; ++e) {
    const int par = e & 1;
    char* fmp = fastmp + par*(512*1024);
    char* smp = slowmp + par*(512*1024);

    // ---- Phase A: cos/sin(pw) -> csf (fp32) + A1 (bf16 swizzled, rows 0..7)
    {
      const int b = tid >> 5, nb = (tid & 31) << 2;
      f32x4 pv = *(const f32x4*)(pws + b*128 + nb);
      f32x4 cv, sv; u16x4 ch, sh;
      #pragma unroll
      for (int u = 0; u < 4; ++u) {
        float ss, cc; sincosf(pv[u], &ss, &cc);
        cv[u] = cc; sv[u] = ss;
        ch[u] = f2bf(cc); sh[u] = f2bf(ss);
      }
      *(f32x4*)(csf + b*128 + nb)        = cv;
      *(f32x4*)(csf + 1024 + b*128 + nb) = sv;
      const int chunk = nb >> 3, lo = (nb & 7)*2;
      *(u16x4*)(A1c + b*512 + ((chunk        ^ b) << 4) + lo) = ch; // k = nb   (cos half)
      *(u16x4*)(A1c + b*512 + (((16 + chunk) ^ b) << 4) + lo) = sh; // k = nb+128 (sin half)
    }
    __syncthreads();

    // ---- Phase B: GEMM1 -> dual publish (slow sc1 store first = longest ack; fast swap)
    {
      bf16x8 bfr[8];
      #pragma unroll
      for (int kk = 0; kk < 8; ++kk)
        bfr[kk] = *(const bf16x8*)(A1c + b16*512 + (((kk*4 + q) ^ b16) << 4));
      f32x4 a0 = {0.f,0.f,0.f,0.f}, a1 = {0.f,0.f,0.f,0.f};
      #pragma unroll
      for (int kk = 0; kk < 8; ++kk) {
        a0 = __builtin_amdgcn_mfma_f32_16x16x32_bf16(t1f[0][kk], bfr[kk], a0, 0, 0, 0);
        a1 = __builtin_amdgcn_mfma_f32_16x16x32_bf16(t1f[1][kk], bfr[kk], a1, 0, 0, 0);
      }
      if (b16 < 8) { // D cols b16>=8 are padding. Partial layout: [b (8)][P (128)] bf16.
        const size_t off0 = (size_t)slot*2048 + (size_t)(b16*128 + (wave*2+0)*16 + q*4)*2;
        const size_t off1 = (size_t)slot*2048 + (size_t)(b16*128 + (wave*2+1)*16 + q*4)*2;
        unsigned long long v0 = pack4bf(a0[0],a0[1],a0[2],a0[3]);
        unsigned long long v1 = pack4bf(a1[0],a1[1],a1[2],a1[3]);
        __hip_atomic_store((unsigned long long*)(smp + off0), v0,
                           __ATOMIC_RELAXED, __HIP_MEMORY_SCOPE_AGENT);
        __hip_atomic_store((unsigned long long*)(smp + off1), v1,
                           __ATOMIC_RELAXED, __HIP_MEMORY_SCOPE_AGENT);
        unsigned long long o0 = __hip_atomic_exchange((unsigned long long*)(fmp + off0), v0,
                           __ATOMIC_RELAXED, __HIP_MEMORY_SCOPE_WORKGROUP);
        unsigned long long o1 = __hip_atomic_exchange((unsigned long long*)(fmp + off1), v1,
                           __ATOMIC_RELAXED, __HIP_MEMORY_SCOPE_WORKGROUP);
        (void)o0; (void)o1;
      }
    }
    __syncthreads();   // vmcnt(0): both publishes at their coherence points
    {
      const int fastNow = modeSh;
      if (tid == 0) {  // dual flag publish
        unsigned o = __hip_atomic_exchange(fastF + slot*8, (unsigned)(e + 1),
                                           __ATOMIC_RELAXED, __HIP_MEMORY_SCOPE_WORKGROUP);
        (void)o;
        __hip_atomic_store(slowF + slot*4, (unsigned)(e + 2),
                           __ATOMIC_RELAXED, __HIP_MEMORY_SCOPE_AGENT);
      }
      if (fastNow && tid < 8) {  // fast poll (L2 RMW), capped -> sticky downgrade
        int it = 0; bool got = false;
        while (it < FAST_TIMEOUT) {
          unsigned v = __hip_atomic_fetch_add(fastF + (g*8 + tid)*8, 0u,
                                              __ATOMIC_RELAXED, __HIP_MEMORY_SCOPE_WORKGROUP);
          if (v >= (unsigned)(e + 1)) { got = true; break; }
          ++it;
          __builtin_amdgcn_s_sleep(1);
        }
        unsigned long long bl = __ballot(got);
        if (tid == 0 && (bl & 0xFFull) != 0xFFull) modeSh = 0;
      }
      __syncthreads();
      if (!modeSh && tid < 8) {  // slow poll (covers slow mode and fresh downgrade)
        while (__hip_atomic_load(slowF + (g*8 + tid)*4,
                                 __ATOMIC_RELAXED, __HIP_MEMORY_SCOPE_AGENT)
               < (unsigned)(e + 2))
          __builtin_amdgcn_s_sleep(1);
      }
      __syncthreads();
    }

    // ---- Phase C: reduce 8 partials (redundant) + softmax -> wtc
    {
      const int mode2 = modeSh;
      const int b = tid >> 5, pb = (tid & 31) << 2;
      const size_t roff = (size_t)(b*128 + pb)*2;
      f32x4 ms = {0.f,0.f,0.f,0.f};
      if (mode2) {
        #pragma unroll
        for (int jj = 0; jj < 8; ++jj) {
          unsigned long long v = __hip_atomic_fetch_add(
              (unsigned long long*)(fmp + (size_t)(g*8 + jj)*2048 + roff), 0ull,
              __ATOMIC_RELAXED, __HIP_MEMORY_SCOPE_WORKGROUP);
          ms[0] += ubf((unsigned short)v);
          ms[1] += ubf((unsigned short)(v >> 16));
          ms[2] += ubf((unsigned short)(v >> 32));
          ms[3] += ubf((unsigned short)(v >> 48));
        }
      } else {
        #pragma unroll
        for (int jj = 0; jj < 8; ++jj) {
          unsigned long long v = __hip_atomic_load(
              (const unsigned long long*)(smp + (size_t)(g*8 + jj)*2048 + roff),
              __ATOMIC_RELAXED, __HIP_MEMORY_SCOPE_AGENT);
          ms[0] += ubf((unsigned short)v);
          ms[1] += ubf((unsigned short)(v >> 16));
          ms[2] += ubf((unsigned short)(v >> 32));
          ms[3] += ubf((unsigned short)(v >> 48));
        }
      }
      f32x4 ev;
      #pragma unroll
      for (int u = 0; u < 4; ++u) ev[u] = __expf(ms[u] * 0.001953125f); // BETA/N = 2/1024
      float s4 = ev[0]+ev[1]+ev[2]+ev[3];
      #pragma unroll
      for (int off = 1; off < 32; off <<= 1) s4 += __shfl_xor(s4, off, 32);
      const float inv = 1.0f / s4;
      u16x4 wq;
      #pragma unroll
      for (int u = 0; u < 4; ++u) wq[u] = f2bf(ev[u]*inv);
      const int chunk = pb >> 3;
      *(u16x4*)(wtc + b*256 + (((chunk ^ b) & 15) << 4) + (pb & 7)*2) = wq;
    }
    __syncthreads();

    // ---- Phase D: GEMM2 -> coup (overlay A1c; A1 dead after Phase B)
    {
      bf16x8 wfr[4];
      #pragma unroll
      for (int kk = 0; kk < 4; ++kk)
        wfr[kk] = *(const bf16x8*)(wtc + b16*256 + ((((kk*4 + q) ^ b16) & 15) << 4));
      f32x4 ac[4];
      #pragma unroll
      for (int u = 0; u < 4; ++u) ac[u] = (f32x4){0.f,0.f,0.f,0.f};
      #pragma unroll
      for (int kk = 0; kk < 4; ++kk) {
        #pragma unroll
        for (int u = 0; u < 4; ++u)
          ac[u] = __builtin_amdgcn_mfma_f32_16x16x32_bf16(t2f[u][kk], wfr[kk], ac[u], 0, 0, 0);
      }
      float* cp = (float*)A1c;   // coup[sc][b][n], row stride 132 (padded, bank-friendly)
      if (b16 < 8) {
        #pragma unroll
        for (int u = 0; u < 4; ++u) {
          const int c  = (wave + 4*u)*16 + q*4;
          const int sc2 = c >> 7, nl = c & 127;
          #pragma unroll
          for (int r = 0; r < 4; ++r)
            cp[sc2*1056 + b16*132 + nl + r] = ac[u][r];
        }
      }
    }
    __syncthreads();

    // ---- Phase E: combine + RK4 update (fp32)
    {
      const int b = tid >> 5, nb = (tid & 31) << 2;
      const float* cp = (const float*)A1c;
      f32x4 wc = *(const f32x4*)(cp + b*132 + nb);
      f32x4 wsv = *(const f32x4*)(cp + 1056 + b*132 + nb);
      f32x4 cf = *(const f32x4*)(csf + b*128 + nb);
      f32x4 sf = *(const f32x4*)(csf + 1024 + b*128 + nb);
      const float swt = tc.s[e], cwt = tc.c[e];
      f32x4 kv;
      #pragma unroll
      for (int u = 0; u < 4; ++u)
        kv[u] = (sf[u]*wc[u] - cf[u]*wsv[u])              // K_COUP = 1
              + 0.08f*(swt*cf[u] - cwt*sf[u]);            // A*sin(wt - phi)
      f32x4 ph0 = *(const f32x4*)(phi0s + b*128 + nb);
      const int st = e & 3;
      f32x4 ka, pw;
      if (st == 0)      { ka = kv;                                              pw = ph0 + kv*half; }
      else if (st == 1) { ka = *(const f32x4*)(kaccs + b*128 + nb) + kv*2.0f;   pw = ph0 + kv*half; }
      else if (st == 2) { ka = *(const f32x4*)(kaccs + b*128 + nb) + kv*2.0f;   pw = ph0 + kv*dtf; }
      else {
        ka = *(const f32x4*)(kaccs + b*128 + nb) + kv;
        f32x4 pn = ph0 + ka*sixth;
        pw = pn;
        *(f32x4*)(phi0s + b*128 + nb) = pn;
      }
      *(f32x4*)(kaccs + b*128 + nb) = ka;
      *(f32x4*)(pws   + b*128 + nb) = pw;
    }
    __syncthreads();
  }

  // ---- epilogue: readout  out = [cos phiT, sin phiT] @ W_out^T + b_out
  {
    const int b = tid >> 5, nb = (tid & 31) << 2;
    f32x4 ph = *(const f32x4*)(phi0s + b*128 + nb);
    float part[10];
    #pragma unroll
    for (int cl = 0; cl < 10; ++cl) part[cl] = 0.0f;
    #pragma unroll
    for (int u = 0; u < 4; ++u) {
      float ss, cc; sincosf(ph[u], &ss, &cc);
      const int ng = jn0 + nb + u;
      #pragma unroll
      for (int cl = 0; cl < 10; ++cl)
        part[cl] += cc * W_out[cl*2048 + ng] + ss * W_out[cl*2048 + 1024 + ng];
    }
    #pragma unroll
    for (int off = 16; off >= 1; off >>= 1) {
      #pragma unroll
      for (int cl = 0; cl < 10; ++cl)
        part[cl] += __shfl_xor(part[cl], off, 32);
    }
    if ((tid & 31) == 0) {
      const int row = g*8 + b;
      #pragma unroll
      for (int cl = 0; cl < 10; ++cl) {
        float v = part[cl];
        if (j == 0) v += b_out[cl];
        atomicAdd(dout + row*10 + cl, v);
      }
    }
  }
}

extern "C" void kernel_launch(void* const* d_in, const int* in_sizes, int n_in,
                              void* d_out, int out_size, void* d_ws, size_t ws_size,
                              hipStream_t stream) {
  (void)in_sizes; (void)n_in; (void)ws_size;
  const float* x     = (const float*)d_in[0];
  const float* W_enc = (const float*)d_in[1];
  const float* b_enc = (const float*)d_in[2];
  const float* xi    = (const float*)d_in[3];
  const float* W_out = (const float*)d_in[4];
  const float* b_out = (const float*)d_in[5];
  float* out = (float*)d_out;

  char* wsb = (char*)d_ws;                               // [0,1M) fast pm, [1M,2M) slow pm
  unsigned int* ctrl = (unsigned int*)(wsb + (2 << 20)); // 16 KiB: fastF/slowF/probe

  hipMemsetAsync(d_out, 0, (size_t)out_size * sizeof(float), stream);
  hipMemsetAsync(ctrl, 0, 16*1024, stream);

  TCons tc;
  const double OME = 2.0 * 3.14159265358979323846 * 200.0;
  const double dtd = 0.03125;
  const double co[4] = {0.0, 0.5, 0.5, 1.0};
  for (int e = 0; e < 64; ++e) {
    double t = ((double)(e >> 2) + co[e & 3]) * dtd;
    tc.s[e] = (float)sin(OME * t);
    tc.c[e] = (float)cos(OME * t);
  }

  phasenn_kernel<<<dim3(256), dim3(256), 0, stream>>>(
      x, W_enc, b_enc, xi, W_out, b_out, out, wsb, ctrl, tc);
}

// Round 7
// 942.612 us; speedup vs baseline: 11.8313x; 11.8313x over previous
//
#include <hip/hip_runtime.h>
#include <math.h>

// PhaseNN: phase-oscillator ODE integrator on MI355X.
// Design:
//   grid = 256 blocks = 32 row-groups (8 batch rows) x 8 N-slices (128 cols), 256 thr/block.
//   cos/sin(xi) slice tables pre-converted to bf16 MFMA A-fragments held in REGISTERS.
//   Per eval: pack cos/sin(phi) -> GEMM1 (m partial, 16x16x32 bf16 MFMA) -> SELF-TAGGED
//   data exchange (single visibility hop) -> redundant reduce + softmax -> GEMM2 ->
//   RK4 combine (fp32).  64 evals.
// Exchange history:
//   R2: relaxed agent atomics + flag barrier: 12.4 us/eval (5 sequential IF$ round trips).
//   R5: byte cut 5x (bf16, stripe split): 12 us/eval -> LATENCY-bound, not BW-bound.
//   R6: L2 atomic-RMW path: CATASTROPHE (RMWs serialize in TCC; 33M RMWs ~ 10 ms).
//       Lesson: never use atomic RMW as a read primitive.
//   R7 (this): SELF-TAGGED WORDS. Each 64-bit word = [tag=e+1 | 2 x bf16 partial].
//       Producers: 4 relaxed agent atomic stores right after MFMA - no drain, no flag,
//       no barrier. Consumers: poll their own 16 words (8 slots x 2) directly; word
//       atomicity makes tag=>data safe; parity double-buffer gives stale tag e-1 != e+1.
//       One visibility hop instead of five. Zero RMWs, zero asm, zero mode probes.
// ws: 2 MiB pm only (2 parity x 256 slots x 4 KiB self-tagged words).

typedef __attribute__((ext_vector_type(4))) float f32x4;
typedef __attribute__((ext_vector_type(8))) short bf16x8;
typedef __attribute__((ext_vector_type(4))) unsigned short u16x4;

struct TCons { float s[64]; float c[64]; };

__device__ __forceinline__ unsigned short f2bf(float f) {
  unsigned u = __builtin_bit_cast(unsigned, f);
  return (unsigned short)((u + 0x7FFFu + ((u >> 16) & 1u)) >> 16);
}
__device__ __forceinline__ float ubf(unsigned short u) {
  unsigned x = ((unsigned)u) << 16;
  return __builtin_bit_cast(float, x);
}

__global__ __launch_bounds__(256, 1) void phasenn_kernel(
    const float* __restrict__ x, const float* __restrict__ W_enc,
    const float* __restrict__ b_enc, const float* __restrict__ xi,
    const float* __restrict__ W_out, const float* __restrict__ b_out,
    float* __restrict__ dout, char* __restrict__ wsb, TCons tc)
{
  __shared__ __align__(16) char  A1c[8448];   // A1 (16x256 bf16, swizzled) / coup (2x8x132 f32) overlay
  __shared__ __align__(16) char  wtc[4096];   // w  (16x128 bf16, swizzled; pad rows zero)
  __shared__ __align__(16) float csf[2048];   // [0..1023]=cos(pw), [1024..2047]=sin(pw), fp32
  __shared__ __align__(16) float phi0s[1024]; // 8 rows x 128 cols
  __shared__ __align__(16) float kaccs[1024];
  __shared__ __align__(16) float pws[1024];
  __shared__ __align__(16) float xst[8*784];  // staged x rows (encoder only)

  const int tid  = threadIdx.x;
  const int g    = blockIdx.x & 31;   // row-group
  const int j    = blockIdx.x >> 5;   // N-slice
  const int jn0  = j << 7;
  const int wave = tid >> 6;
  const int lane = tid & 63;
  const int b16  = lane & 15;
  const int q    = lane >> 4;
  const int slot = g*8 + j;

  // ---- prologue: zero w-table (pad rows b>=8 must stay 0)
  for (int idx = tid; idx < 2048; idx += 256) ((unsigned short*)wtc)[idx] = 0;

  // ---- prologue: stage x rows into LDS
  for (int idx = tid; idx < 8*784; idx += 256) {
    int bb = idx / 784;
    xst[idx] = x[(g*8 + bb)*784 + (idx - bb*784)];
  }
  __syncthreads();

  // ---- prologue: encoder  phi0 = 2pi*sigmoid(x @ W_enc^T + b_enc)  (fp32 VALU)
  {
    const int b = tid >> 5, nl = (tid & 31) << 2;
    #pragma unroll
    for (int u = 0; u < 4; ++u) {
      const int ng = jn0 + nl + u;
      const float* wr = W_enc + ng*784;
      const float* xr = xst + b*784;
      float acc = b_enc[ng];
      #pragma unroll 4
      for (int d = 0; d < 784; d += 4) {
        f32x4 wv = *(const f32x4*)(wr + d);
        f32x4 xv = *(const f32x4*)(xr + d);
        acc += wv[0]*xv[0] + wv[1]*xv[1] + wv[2]*xv[2] + wv[3]*xv[3];
      }
      float ph = 6.283185307179586f / (1.0f + __expf(-acc));
      phi0s[b*128 + nl + u] = ph;
      pws  [b*128 + nl + u] = ph;
    }
  }

  // ---- prologue: build table fragments in registers (bf16)
  // GEMM1 (transposed): D[p][b] = sum_k T1[p][k] * A1[k][b]
  bf16x8 t1f[2][8];
  #pragma unroll
  for (int tt = 0; tt < 2; ++tt) {
    const int p = (wave*2 + tt)*16 + b16;
    #pragma unroll
    for (int kk = 0; kk < 8; ++kk) {
      const int base = (kk & 3)*32 + q*8;
      const float* src = xi + p*1024 + jn0 + base;
      f32x4 v0 = *(const f32x4*)(src);
      f32x4 v1 = *(const f32x4*)(src + 4);
      bf16x8 fr;
      #pragma unroll
      for (int i = 0; i < 8; ++i) {
        float xv = (i < 4) ? v0[i] : v1[i-4];
        float t  = (kk < 4) ? cosf(xv) : sinf(xv);
        fr[i] = (short)f2bf(t);
      }
      t1f[tt][kk] = fr;
    }
  }
  // GEMM2 (transposed): D[c][b] = sum_p T2[c][p] * w[p][b]
  bf16x8 t2f[4][4];
  #pragma unroll
  for (int u = 0; u < 4; ++u) {
    const int c   = (wave + 4*u)*16 + b16;
    const int col = jn0 + (c & 127);
    const bool isc = (c < 128);
    #pragma unroll
    for (int kk = 0; kk < 4; ++kk) {
      bf16x8 fr;
      #pragma unroll
      for (int i = 0; i < 8; ++i) {
        const int p = kk*32 + q*8 + i;
        float xv = xi[p*1024 + col];
        fr[i] = (short)f2bf(isc ? cosf(xv) : sinf(xv));
      }
      t2f[u][kk] = fr;
    }
  }
  __syncthreads();

  const float dtf = 0.03125f, half = 0.015625f;
  const float sixth = (float)(0.03125/6.0);

  for (int e = 0; e < 64; ++e) {
    char* mp = wsb + (e & 1)*(1 << 20);   // parity buffer: 256 slots x 4 KiB

    // ---- Phase A: cos/sin(pw) -> csf (fp32) + A1 (bf16 swizzled, rows 0..7)
    {
      const int b = tid >> 5, nb = (tid & 31) << 2;
      f32x4 pv = *(const f32x4*)(pws + b*128 + nb);
      f32x4 cv, sv; u16x4 ch, sh;
      #pragma unroll
      for (int u = 0; u < 4; ++u) {
        float ss, cc; sincosf(pv[u], &ss, &cc);
        cv[u] = cc; sv[u] = ss;
        ch[u] = f2bf(cc); sh[u] = f2bf(ss);
      }
      *(f32x4*)(csf + b*128 + nb)        = cv;
      *(f32x4*)(csf + 1024 + b*128 + nb) = sv;
      const int chunk = nb >> 3, lo = (nb & 7)*2;
      *(u16x4*)(A1c + b*512 + ((chunk        ^ b) << 4) + lo) = ch; // k = nb   (cos half)
      *(u16x4*)(A1c + b*512 + (((16 + chunk) ^ b) << 4) + lo) = sh; // k = nb+128 (sin half)
    }
    __syncthreads();

    // ---- Phase B: GEMM1 -> publish SELF-TAGGED words (no drain, no flag, no barrier)
    {
      bf16x8 bfr[8];
      #pragma unroll
      for (int kk = 0; kk < 8; ++kk)
        bfr[kk] = *(const bf16x8*)(A1c + b16*512 + (((kk*4 + q) ^ b16) << 4));
      f32x4 a0 = {0.f,0.f,0.f,0.f}, a1 = {0.f,0.f,0.f,0.f};
      #pragma unroll
      for (int kk = 0; kk < 8; ++kk) {
        a0 = __builtin_amdgcn_mfma_f32_16x16x32_bf16(t1f[0][kk], bfr[kk], a0, 0, 0, 0);
        a1 = __builtin_amdgcn_mfma_f32_16x16x32_bf16(t1f[1][kk], bfr[kk], a1, 0, 0, 0);
      }
      if (b16 < 8) { // D cols b16>=8 are padding.
        // Word layout per slot: [row b (8)][word (64)] x 8 B; word w holds p=2w,2w+1.
        char* sbase = mp + (size_t)slot*4096 + (size_t)(b16*64)*8;
        const unsigned long long tg = ((unsigned long long)(unsigned)(e + 1)) << 32;
        const int w0 = wave*16 + q*2;       // a0: p = wave*32 + q*4 + r
        const int w1 = wave*16 + 8 + q*2;   // a1: p = wave*32 + 16 + q*4 + r
        unsigned long long v00 = tg | (unsigned long long)f2bf(a0[0])
                               | ((unsigned long long)f2bf(a0[1]) << 16);
        unsigned long long v01 = tg | (unsigned long long)f2bf(a0[2])
                               | ((unsigned long long)f2bf(a0[3]) << 16);
        unsigned long long v10 = tg | (unsigned long long)f2bf(a1[0])
                               | ((unsigned long long)f2bf(a1[1]) << 16);
        unsigned long long v11 = tg | (unsigned long long)f2bf(a1[2])
                               | ((unsigned long long)f2bf(a1[3]) << 16);
        __hip_atomic_store((unsigned long long*)(sbase + (size_t)w0*8),       v00,
                           __ATOMIC_RELAXED, __HIP_MEMORY_SCOPE_AGENT);
        __hip_atomic_store((unsigned long long*)(sbase + (size_t)(w0 + 1)*8), v01,
                           __ATOMIC_RELAXED, __HIP_MEMORY_SCOPE_AGENT);
        __hip_atomic_store((unsigned long long*)(sbase + (size_t)w1*8),       v10,
                           __ATOMIC_RELAXED, __HIP_MEMORY_SCOPE_AGENT);
        __hip_atomic_store((unsigned long long*)(sbase + (size_t)(w1 + 1)*8), v11,
                           __ATOMIC_RELAXED, __HIP_MEMORY_SCOPE_AGENT);
      }
    }
    // NO barrier: consumers poll the self-tagged data directly.

    // ---- Phase C: poll own words (8 slots x 2), reduce, softmax -> wtc
    {
      const int b = tid >> 5, pb = (tid & 31) << 2;
      const char* gbase = mp + (size_t)(g*8)*4096 + (size_t)(b*64 + (pb >> 1))*8;
      const unsigned tagv = (unsigned)(e + 1);
      f32x4 ms = {0.f,0.f,0.f,0.f};
      unsigned long long w[16];
      unsigned need = 0;
      #pragma unroll
      for (int i = 0; i < 16; ++i) {   // 16 loads issued back-to-back (pipelined)
        const unsigned long long* ap =
            (const unsigned long long*)(gbase + (size_t)(i >> 1)*4096 + (size_t)(i & 1)*8);
        w[i] = __hip_atomic_load(ap, __ATOMIC_RELAXED, __HIP_MEMORY_SCOPE_AGENT);
      }
      #pragma unroll
      for (int i = 0; i < 16; ++i) {
        if ((unsigned)(w[i] >> 32) == tagv) {
          const int h = (i & 1) << 1;
          ms[h]   += ubf((unsigned short)w[i]);
          ms[h+1] += ubf((unsigned short)(w[i] >> 16));
        } else need |= (1u << i);
      }
      while (need) {
        __builtin_amdgcn_s_sleep(1);
        #pragma unroll
        for (int i = 0; i < 16; ++i) {
          if (need & (1u << i)) {
            const unsigned long long* ap =
                (const unsigned long long*)(gbase + (size_t)(i >> 1)*4096 + (size_t)(i & 1)*8);
            unsigned long long v = __hip_atomic_load(ap, __ATOMIC_RELAXED,
                                                     __HIP_MEMORY_SCOPE_AGENT);
            if ((unsigned)(v >> 32) == tagv) {
              const int h = (i & 1) << 1;
              ms[h]   += ubf((unsigned short)v);
              ms[h+1] += ubf((unsigned short)(v >> 16));
              need &= ~(1u << i);
            }
          }
        }
      }
      f32x4 ev;
      #pragma unroll
      for (int u = 0; u < 4; ++u) ev[u] = __expf(ms[u] * 0.001953125f); // BETA/N = 2/1024
      float s4 = ev[0]+ev[1]+ev[2]+ev[3];
      #pragma unroll
      for (int off = 1; off < 32; off <<= 1) s4 += __shfl_xor(s4, off, 32);
      const float inv = 1.0f / s4;
      u16x4 wq;
      #pragma unroll
      for (int u = 0; u < 4; ++u) wq[u] = f2bf(ev[u]*inv);
      const int chunk = pb >> 3;
      *(u16x4*)(wtc + b*256 + (((chunk ^ b) & 15) << 4) + (pb & 7)*2) = wq;
    }
    __syncthreads();

    // ---- Phase D: GEMM2 -> coup (overlay A1c; A1 dead after Phase B)
    {
      bf16x8 wfr[4];
      #pragma unroll
      for (int kk = 0; kk < 4; ++kk)
        wfr[kk] = *(const bf16x8*)(wtc + b16*256 + ((((kk*4 + q) ^ b16) & 15) << 4));
      f32x4 ac[4];
      #pragma unroll
      for (int u = 0; u < 4; ++u) ac[u] = (f32x4){0.f,0.f,0.f,0.f};
      #pragma unroll
      for (int kk = 0; kk < 4; ++kk) {
        #pragma unroll
        for (int u = 0; u < 4; ++u)
          ac[u] = __builtin_amdgcn_mfma_f32_16x16x32_bf16(t2f[u][kk], wfr[kk], ac[u], 0, 0, 0);
      }
      float* cp = (float*)A1c;   // coup[sc][b][n], row stride 132 (padded, bank-friendly)
      if (b16 < 8) {
        #pragma unroll
        for (int u = 0; u < 4; ++u) {
          const int c  = (wave + 4*u)*16 + q*4;
          const int sc2 = c >> 7, nl = c & 127;
          #pragma unroll
          for (int r = 0; r < 4; ++r)
            cp[sc2*1056 + b16*132 + nl + r] = ac[u][r];
        }
      }
    }
    __syncthreads();

    // ---- Phase E: combine + RK4 update (fp32)
    {
      const int b = tid >> 5, nb = (tid & 31) << 2;
      const float* cp = (const float*)A1c;
      f32x4 wc = *(const f32x4*)(cp + b*132 + nb);
      f32x4 wsv = *(const f32x4*)(cp + 1056 + b*132 + nb);
      f32x4 cf = *(const f32x4*)(csf + b*128 + nb);
      f32x4 sf = *(const f32x4*)(csf + 1024 + b*128 + nb);
      const float swt = tc.s[e], cwt = tc.c[e];
      f32x4 kv;
      #pragma unroll
      for (int u = 0; u < 4; ++u)
        kv[u] = (sf[u]*wc[u] - cf[u]*wsv[u])              // K_COUP = 1
              + 0.08f*(swt*cf[u] - cwt*sf[u]);            // A*sin(wt - phi)
      f32x4 ph0 = *(const f32x4*)(phi0s + b*128 + nb);
      const int st = e & 3;
      f32x4 ka, pw;
      if (st == 0)      { ka = kv;                                              pw = ph0 + kv*half; }
      else if (st == 1) { ka = *(const f32x4*)(kaccs + b*128 + nb) + kv*2.0f;   pw = ph0 + kv*half; }
      else if (st == 2) { ka = *(const f32x4*)(kaccs + b*128 + nb) + kv*2.0f;   pw = ph0 + kv*dtf; }
      else {
        ka = *(const f32x4*)(kaccs + b*128 + nb) + kv;
        f32x4 pn = ph0 + ka*sixth;
        pw = pn;
        *(f32x4*)(phi0s + b*128 + nb) = pn;
      }
      *(f32x4*)(kaccs + b*128 + nb) = ka;
      *(f32x4*)(pws   + b*128 + nb) = pw;
    }
    __syncthreads();
  }

  // ---- epilogue: readout  out = [cos phiT, sin phiT] @ W_out^T + b_out
  {
    const int b = tid >> 5, nb = (tid & 31) << 2;
    f32x4 ph = *(const f32x4*)(phi0s + b*128 + nb);
    float part[10];
    #pragma unroll
    for (int cl = 0; cl < 10; ++cl) part[cl] = 0.0f;
    #pragma unroll
    for (int u = 0; u < 4; ++u) {
      float ss, cc; sincosf(ph[u], &ss, &cc);
      const int ng = jn0 + nb + u;
      #pragma unroll
      for (int cl = 0; cl < 10; ++cl)
        part[cl] += cc * W_out[cl*2048 + ng] + ss * W_out[cl*2048 + 1024 + ng];
    }
    #pragma unroll
    for (int off = 16; off >= 1; off >>= 1) {
      #pragma unroll
      for (int cl = 0; cl < 10; ++cl)
        part[cl] += __shfl_xor(part[cl], off, 32);
    }
    if ((tid & 31) == 0) {
      const int row = g*8 + b;
      #pragma unroll
      for (int cl = 0; cl < 10; ++cl) {
        float v = part[cl];
        if (j == 0) v += b_out[cl];
        atomicAdd(dout + row*10 + cl, v);
      }
    }
  }
}

extern "C" void kernel_launch(void* const* d_in, const int* in_sizes, int n_in,
                              void* d_out, int out_size, void* d_ws, size_t ws_size,
                              hipStream_t stream) {
  (void)in_sizes; (void)n_in; (void)ws_size;
  const float* x     = (const float*)d_in[0];
  const float* W_enc = (const float*)d_in[1];
  const float* b_enc = (const float*)d_in[2];
  const float* xi    = (const float*)d_in[3];
  const float* W_out = (const float*)d_in[4];
  const float* b_out = (const float*)d_in[5];
  float* out = (float*)d_out;

  char* wsb = (char*)d_ws;   // 2 MiB self-tagged exchange buffer; 0xAA poison is a
                             // non-matching tag, so no memset needed for it.

  hipMemsetAsync(d_out, 0, (size_t)out_size * sizeof(float), stream);

  TCons tc;
  const double OME = 2.0 * 3.14159265358979323846 * 200.0;
  const double dtd = 0.03125;
  const double co[4] = {0.0, 0.5, 0.5, 1.0};
  for (int e = 0; e < 64; ++e) {
    double t = ((double)(e >> 2) + co[e & 3]) * dtd;
    tc.s[e] = (float)sin(OME * t);
    tc.c[e] = (float)cos(OME * t);
  }

  phasenn_kernel<<<dim3(256), dim3(256), 0, stream>>>(
      x, W_enc, b_enc, xi, W_out, b_out, out, wsb, tc);
}